// Round 7
// baseline (38.896 us; speedup 1.0000x reference)
//
#include <hip/hip_runtime.h>

typedef float float2v __attribute__((ext_vector_type(2)));

#define LDSPTS 2048
#define REP 3   // work-multiplier probe: compute loop runs REP times, result scaled by 1/REP

__device__ __forceinline__ float exp2fast(float x) {
#if __has_builtin(__builtin_amdgcn_exp2f)
    return __builtin_amdgcn_exp2f(x);
#else
    return __expf(x * 0.6931471805599453f);
#endif
}
__device__ __forceinline__ float rsqfast(float x) {
#if __has_builtin(__builtin_amdgcn_rsqf)
    return __builtin_amdgcn_rsqf(x);
#else
    return rsqrtf(x);
#endif
}

// R6 structure (passed, 19.4us), plus REP-x inner-loop repetition as a
// floor-vs-work ablation probe. acc accumulates REP identical passes; the
// final scale folds in 1/REP so the output is unchanged (±1 ulp).
__global__ __launch_bounds__(256, 4) void sph_one(
    const float* __restrict__ f, const float* __restrict__ coords,
    const float* __restrict__ out_coords, const float* __restrict__ mu,
    const float* __restrict__ r_norms, const float* __restrict__ a0,
    const float* __restrict__ a1, float* __restrict__ out, int N, int A)
{
    __shared__ float sF[LDSPTS], sX[LDSPTS], sY[LDSPTS], sZ[LDSPTS];
    __shared__ float red[2][64];

    const int tid  = threadIdx.x;
    const int lane = tid & 63;
    const int w    = tid >> 6;
    const int pa   = w >> 1;
    const int ih   = w & 1;
    const int a    = blockIdx.x * 2 + pa;
    const bool act = (a < A);

    float ox = 0.f, oy = 0.f, oz = 0.f;
    if (act) {
        ox = out_coords[3 * a + 0];
        oy = out_coords[3 * a + 1];
        oz = out_coords[3 * a + 2];
    }

    const float L2E = 1.44269504088896340736f;
    const float k16 = -L2E * mu[15], k12 = -L2E * mu[11];
    const float k9  = -L2E * mu[8],  k10 = -L2E * mu[9],  k11 = -L2E * mu[10];
    const float k13 = -L2E * mu[12], k14 = -L2E * mu[13], k15 = -L2E * mu[14];

    float2v acc2[32];
#pragma unroll
    for (int j = 0; j < 32; ++j) { acc2[j].x = 0.f; acc2[j].y = 0.f; }

    for (int base = 0; base < N; base += LDSPTS) {
        const int seg = min(LDSPTS, N - base);
        __syncthreads();
        for (int idx = tid; idx < seg; idx += 256) {
            const int gi = base + idx;
            sF[idx] = f[gi];
            sX[idx] = coords[3 * gi + 0];
            sY[idx] = coords[3 * gi + 1];
            sZ[idx] = coords[3 * gi + 2];
        }
        __syncthreads();
        if (act) {
            for (int rep = 0; rep < REP; ++rep) {
#pragma unroll 2
                for (int t = lane + (ih << 6); t < seg; t += 128) {
                    const float fi = sF[t];
                    const float dx = sX[t] - ox;
                    const float dy = sY[t] - oy;
                    const float dz = sZ[t] - oz;
                    const float r2 = fmaf(dx, dx, fmaf(dy, dy, dz * dz));
                    const float rinv = rsqfast(r2);
                    const float r  = r2 * rinv;
                    const float fr = fi * rinv;
                    float2v v01, v23;
                    v01.x = fi;      v01.y = fr * dx;
                    v23.x = fr * dy; v23.y = fr * dz;

                    float e[16];
                    e[15] = exp2fast(k16 * r);
                    e[11] = exp2fast(k12 * r);
                    e[8]  = exp2fast(k9  * r);
                    e[9]  = exp2fast(k10 * r);
                    e[10] = exp2fast(k11 * r);
                    e[12] = exp2fast(k13 * r);
                    e[13] = exp2fast(k14 * r);
                    e[14] = exp2fast(k15 * r);
                    e[7] = e[15] * e[15];
                    e[3] = e[7]  * e[7];
                    e[1] = e[3]  * e[3];
                    e[0] = e[1]  * e[1];
                    e[5] = e[11] * e[11];
                    e[2] = e[5]  * e[5];
                    e[4] = e[9]  * e[9];
                    e[6] = e[13] * e[13];
#pragma unroll
                    for (int s = 0; s < 16; ++s) {
                        float2v es; es.x = e[s]; es.y = e[s];
                        acc2[2 * s + 0] = es * v01 + acc2[2 * s + 0];
                        acc2[2 * s + 1] = es * v23 + acc2[2 * s + 1];
                    }
                }
            }
        }
    }

#pragma unroll
    for (int m2 = 16; m2 >= 1; m2 >>= 1) {
        const int M = m2 * 2;
        const bool hi = (lane & M) != 0;
#pragma unroll
        for (int j = 0; j < m2; ++j) {
            const float2v lo_v = acc2[j];
            const float2v hi_v = acc2[j + m2];
            float gx = hi ? lo_v.x : hi_v.x;
            float gy = hi ? lo_v.y : hi_v.y;
            const float kx = hi ? hi_v.x : lo_v.x;
            const float ky = hi ? hi_v.y : lo_v.y;
            gx = __shfl_xor(gx, M, 64);
            gy = __shfl_xor(gy, M, 64);
            acc2[j].x = kx + gx;
            acc2[j].y = ky + gy;
        }
    }
    const bool h0 = (lane & 1) != 0;
    const float give = h0 ? acc2[0].x : acc2[0].y;
    const float keep = h0 ? acc2[0].y : acc2[0].x;
    const float tot = keep + __shfl_xor(give, 1, 64);

    if (act && ih == 1) red[pa][lane] = tot;
    __syncthreads();
    if (act && ih == 0) {
        const float sum = tot + red[pa][lane];
        const int s = lane >> 2;
        const int c = lane & 3;
        const float inv_rep = 1.0f / (float)REP;
        float scale; int ov;
        if (c == 0) { scale = r_norms[s] * a0[0] * inv_rep; ov = s; }
        else        { scale = r_norms[s] * a1[c - 1] * inv_rep; ov = 16 + 3 * s + (c - 1); }
        out[a * 64 + ov] = sum * scale;
    }
}

extern "C" void kernel_launch(void* const* d_in, const int* in_sizes, int n_in,
                              void* d_out, int out_size, void* d_ws, size_t ws_size,
                              hipStream_t stream) {
    const float* f          = (const float*)d_in[0];
    const float* coords     = (const float*)d_in[1];
    const float* out_coords = (const float*)d_in[2];
    const float* mu         = (const float*)d_in[3];
    const float* r_norms    = (const float*)d_in[4];
    const float* a_norms_0  = (const float*)d_in[5];
    const float* a_norms_1  = (const float*)d_in[6];
    float* out = (float*)d_out;

    const int N = in_sizes[0];
    const int A = in_sizes[2] / 3;

    sph_one<<<(A + 1) / 2, 256, 0, stream>>>(f, coords, out_coords, mu, r_norms,
                                             a_norms_0, a_norms_1, out, N, A);
}

// Round 8
// 22.236 us; speedup vs baseline: 1.7492x; 1.7492x over previous
//
#include <hip/hip_runtime.h>

typedef float float2v __attribute__((ext_vector_type(2)));

__device__ __forceinline__ float exp2fast(float x) {
#if __has_builtin(__builtin_amdgcn_exp2f)
    return __builtin_amdgcn_exp2f(x);
#else
    return __expf(x * 0.6931471805599453f);
#endif
}
__device__ __forceinline__ float rsqfast(float x) {
#if __has_builtin(__builtin_amdgcn_rsqf)
    return __builtin_amdgcn_rsqf(x);
#else
    return rsqrtf(x);
#endif
}

// One dispatch. Block = 256 thr = 4 waves = (scale-group grp) x (i-half ih),
// all for ONE output point a = blockIdx.x. lane = i (stride 128).
// Scale groups (s' = global s + 1; mu_{s'} = C/s' => e_{s'/2} = e_{s'}^2):
//  G0 locals {16,12,8,4,2,1,6,3}: 2 exps + pk-squarings
//  G1 locals {9,10,11,13,14,15,5,7}: 6 exps + 1 pk-squaring
// Epilogue tables verified in R3: G0 nibbles 0x250137BF, G1 0x64EDCA98.
// acc2[16] (32 regs) -> ~75 VGPR/thread -> 6 waves/SIMD at launch_bounds(256,6).
// No LDS staging: inputs are 32KB (~L1-resident); 1-deep manual prefetch
// pipeline hides load latency.
__global__ __launch_bounds__(256, 6) void sph_one(
    const float* __restrict__ f, const float* __restrict__ coords,
    const float* __restrict__ out_coords, const float* __restrict__ mu,
    const float* __restrict__ r_norms, const float* __restrict__ a0,
    const float* __restrict__ a1, float* __restrict__ out, int N, int A)
{
    __shared__ float red[2][32];

    const int tid  = threadIdx.x;
    const int lane = tid & 63;
    const int w    = tid >> 6;
    const int grp  = w >> 1;      // 0 = G0, 1 = G1
    const int ih   = w & 1;       // i-half
    const int a    = blockIdx.x;

    const float ox = out_coords[3 * a + 0];
    const float oy = out_coords[3 * a + 1];
    const float oz = out_coords[3 * a + 2];

    const float L2E = 1.44269504088896340736f;
    float2v kA = {0.f, 0.f}, kB = {0.f, 0.f}, kC = {0.f, 0.f};
    if (grp == 0) {
        kA.x = -L2E * mu[15]; kA.y = -L2E * mu[11];            // s'=16,12
    } else {
        kA.x = -L2E * mu[8];  kA.y = -L2E * mu[9];             // s'=9,10
        kB.x = -L2E * mu[10]; kB.y = -L2E * mu[12];            // s'=11,13
        kC.x = -L2E * mu[13]; kC.y = -L2E * mu[14];            // s'=14,15
    }

    float2v acc2[16];             // local value v=4*sl+c; acc2[2sl]={f,fx}, acc2[2sl+1]={fy,fz}
#pragma unroll
    for (int j = 0; j < 16; ++j) { acc2[j].x = 0.f; acc2[j].y = 0.f; }

    // ---- prefetch-pipelined i-loop (global loads, L1-resident input) ----
    const int t0 = lane + (ih << 6);
    const int niter = (N > t0) ? ((N - (ih << 6) + 127) >> 7) : 0;
    int t = t0;
    int tc = min(t, N - 1);
    float cf = (t < N) ? f[tc] : 0.f;
    float cx = coords[3 * tc + 0];
    float cy = coords[3 * tc + 1];
    float cz = coords[3 * tc + 2];

    for (int it = 0; it < niter; ++it) {
        // issue next-iteration loads first (latency hides under compute)
        const int tn  = t + 128;
        const int tnc = min(tn, N - 1);
        float nf = f[tnc];
        float nx = coords[3 * tnc + 0];
        float ny = coords[3 * tnc + 1];
        float nz = coords[3 * tnc + 2];
        nf = (tn < N) ? nf : 0.f;

        const float dx = cx - ox, dy = cy - oy, dz = cz - oz;
        const float r2 = fmaf(dx, dx, fmaf(dy, dy, dz * dz));
        const float rinv = rsqfast(r2);
        const float r  = r2 * rinv;
        const float fr = cf * rinv;
        float2v v01; v01.x = cf;      v01.y = fr * dx;
        float2v v23; v23.x = fr * dy; v23.y = fr * dz;
        float2v rr;  rr.x = r;        rr.y = r;

        float e[8];
        if (grp == 0) {
            float2v s0 = kA * rr;                       // v_pk_mul
            e[0] = exp2fast(s0.x); e[1] = exp2fast(s0.y);
            float2v p01; p01.x = e[0]; p01.y = e[1];
            float2v p26 = p01 * p01; e[2] = p26.x; e[6] = p26.y;   // s'=8,6
            float2v p37 = p26 * p26; e[3] = p37.x; e[7] = p37.y;   // s'=4,3
            e[4] = e[3] * e[3];                                     // s'=2
            e[5] = e[4] * e[4];                                     // s'=1
        } else {
            float2v sA = kA * rr, sB = kB * rr, sC = kC * rr;
            e[0] = exp2fast(sA.x); e[1] = exp2fast(sA.y);
            e[2] = exp2fast(sB.x); e[3] = exp2fast(sB.y);
            e[4] = exp2fast(sC.x); e[5] = exp2fast(sC.y);
            float2v p14; p14.x = e[1]; p14.y = e[4];
            float2v p67 = p14 * p14; e[6] = p67.x; e[7] = p67.y;   // s'=5,7
        }
#pragma unroll
        for (int sl = 0; sl < 8; ++sl) {
            float2v es; es.x = e[sl]; es.y = e[sl];
            acc2[2 * sl + 0] = es * v01 + acc2[2 * sl + 0];   // v_pk_fma_f32
            acc2[2 * sl + 1] = es * v23 + acc2[2 * sl + 1];
        }

        t = tn; cf = nf; cx = nx; cy = ny; cz = nz;
    }

    // ---- value-split butterfly: 16 float2 -> lane l holds value (l&31) ----
#pragma unroll
    for (int m2 = 8; m2 >= 1; m2 >>= 1) {
        const int M = m2 * 2;
        const bool hi = (lane & M) != 0;
#pragma unroll
        for (int j = 0; j < m2; ++j) {
            const float2v lo_v = acc2[j];
            const float2v hi_v = acc2[j + m2];
            float gx = hi ? lo_v.x : hi_v.x;
            float gy = hi ? lo_v.y : hi_v.y;
            const float kx = hi ? hi_v.x : lo_v.x;
            const float ky = hi ? hi_v.y : lo_v.y;
            gx = __shfl_xor(gx, M, 64);
            gy = __shfl_xor(gy, M, 64);
            acc2[j].x = kx + gx;
            acc2[j].y = ky + gy;
        }
    }
    const bool h0 = (lane & 1) != 0;
    const float give = h0 ? acc2[0].x : acc2[0].y;
    const float keep = h0 ? acc2[0].y : acc2[0].x;
    float tot = keep + __shfl_xor(give, 1, 64);
    tot = tot + __shfl_xor(tot, 32, 64);      // merge the duplicated 32-lane halves

    if (ih == 1 && lane < 32) red[grp][lane] = tot;
    __syncthreads();
    if (ih == 0 && lane < 32) {
        const float sum = tot + red[grp][lane];
        const int sl = lane >> 2;      // local scale slot 0..7
        const int cc = lane & 3;       // 0 = scalar, 1..3 = x/y/z
        const unsigned table = grp ? 0x64EDCA98u : 0x250137BFu;
        const int s = (table >> (sl * 4)) & 0xF;
        float scale; int ov;
        if (cc == 0) { scale = r_norms[s] * a0[0];      ov = s; }
        else         { scale = r_norms[s] * a1[cc - 1]; ov = 16 + 3 * s + (cc - 1); }
        out[a * 64 + ov] = sum * scale;
    }
}

extern "C" void kernel_launch(void* const* d_in, const int* in_sizes, int n_in,
                              void* d_out, int out_size, void* d_ws, size_t ws_size,
                              hipStream_t stream) {
    const float* f          = (const float*)d_in[0];
    const float* coords     = (const float*)d_in[1];
    const float* out_coords = (const float*)d_in[2];
    const float* mu         = (const float*)d_in[3];
    const float* r_norms    = (const float*)d_in[4];
    const float* a_norms_0  = (const float*)d_in[5];
    const float* a_norms_1  = (const float*)d_in[6];
    float* out = (float*)d_out;

    const int N = in_sizes[0];       // f is [B=1, N]
    const int A = in_sizes[2] / 3;   // out_coords is [B=1, A, 3]

    sph_one<<<A, 256, 0, stream>>>(f, coords, out_coords, mu, r_norms,
                                   a_norms_0, a_norms_1, out, N, A);
}

// Round 9
// 19.570 us; speedup vs baseline: 1.9875x; 1.1362x over previous
//
#include <hip/hip_runtime.h>

#define LDSPTS 2048

__device__ __forceinline__ float exp2fast(float x) {
#if __has_builtin(__builtin_amdgcn_exp2f)
    return __builtin_amdgcn_exp2f(x);
#else
    return __expf(x * 0.6931471805599453f);
#endif
}
__device__ __forceinline__ float rsqfast(float x) {
#if __has_builtin(__builtin_amdgcn_rsqf)
    return __builtin_amdgcn_rsqf(x);
#else
    return rsqrtf(x);
#endif
}

// R6 skeleton (best: 19.4us), de-stalled:
//  - scalar acc[64], no ext-vector types (VGPR <= 128 -> 4 blocks/CU by LDS)
//  - LDS AoS float4: 1 ds_read_b128 per point (was 4 ds_read_b32)
//  - manual 1-deep prefetch: next point's LDS read in flight during compute
// Block = 256 thr = 4 waves = 2 output points (pa) x 2 i-halves (ih).
// Each wave: all 16 scales, 8 exp seeds (s'=16,12,9..15) + squaring chain
// (mu_s' = C/s' => e_{s'/2} = e_{s'}^2). R1-verified butterfly: lane l ends
// holding value index l (= 4s + c). R6-verified epilogue layout.
__global__ __launch_bounds__(256, 4) void sph_one(
    const float* __restrict__ f, const float* __restrict__ coords,
    const float* __restrict__ out_coords, const float* __restrict__ mu,
    const float* __restrict__ r_norms, const float* __restrict__ a0,
    const float* __restrict__ a1, float* __restrict__ out, int N, int A)
{
    __shared__ float4 sP[LDSPTS];          // 32 KB
    __shared__ float red[2][64];

    const int tid  = threadIdx.x;
    const int lane = tid & 63;
    const int w    = tid >> 6;
    const int pa   = w >> 1;
    const int ih   = w & 1;
    const int a    = blockIdx.x * 2 + pa;
    const bool act = (a < A);
    const int ac   = act ? a : (A - 1);

    const float ox = out_coords[3 * ac + 0];   // wave-uniform -> s_load
    const float oy = out_coords[3 * ac + 1];
    const float oz = out_coords[3 * ac + 2];

    const float L2E = 1.44269504088896340736f;
    const float k16 = -L2E * mu[15], k12 = -L2E * mu[11];
    const float k9  = -L2E * mu[8],  k10 = -L2E * mu[9],  k11 = -L2E * mu[10];
    const float k13 = -L2E * mu[12], k14 = -L2E * mu[13], k15 = -L2E * mu[14];

    float acc[64];
#pragma unroll
    for (int j = 0; j < 64; ++j) acc[j] = 0.0f;

    for (int base = 0; base < N; base += LDSPTS) {
        const int seg = min(LDSPTS, N - base);
        __syncthreads();
        for (int idx = tid; idx < seg; idx += 256) {
            const int gi = base + idx;
            sP[idx] = make_float4(f[gi], coords[3 * gi + 0],
                                  coords[3 * gi + 1], coords[3 * gi + 2]);
        }
        __syncthreads();
        if (act) {
            const int t0 = lane + (ih << 6);
            if (t0 < seg) {
                float4 cur = sP[t0];           // ds_read_b128
                int t = t0;
                while (true) {
                    const int tn = t + 128;
                    const bool more = (tn < seg);
                    float4 nxt;
                    if (more) nxt = sP[tn];    // issued before compute; latency hidden

                    const float fi = cur.x;
                    const float dx = cur.y - ox;
                    const float dy = cur.z - oy;
                    const float dz = cur.w - oz;
                    const float r2 = fmaf(dx, dx, fmaf(dy, dy, dz * dz));
                    const float rinv = rsqfast(r2);
                    const float r  = r2 * rinv;
                    const float fr = fi * rinv;
                    const float fx = fr * dx, fy = fr * dy, fz = fr * dz;

                    float e[16];               // e[s], global scale s (s' = s+1)
                    e[15] = exp2fast(k16 * r);
                    e[11] = exp2fast(k12 * r);
                    e[8]  = exp2fast(k9  * r);
                    e[9]  = exp2fast(k10 * r);
                    e[10] = exp2fast(k11 * r);
                    e[12] = exp2fast(k13 * r);
                    e[13] = exp2fast(k14 * r);
                    e[14] = exp2fast(k15 * r);
                    e[7] = e[15] * e[15];      // s'=8
                    e[3] = e[7]  * e[7];       // 4
                    e[1] = e[3]  * e[3];       // 2
                    e[0] = e[1]  * e[1];       // 1
                    e[5] = e[11] * e[11];      // 6
                    e[2] = e[5]  * e[5];       // 3
                    e[4] = e[9]  * e[9];       // 5
                    e[6] = e[13] * e[13];      // 7
#pragma unroll
                    for (int s = 0; s < 16; ++s) {
                        acc[4 * s + 0] = fmaf(e[s], fi, acc[4 * s + 0]);
                        acc[4 * s + 1] = fmaf(e[s], fx, acc[4 * s + 1]);
                        acc[4 * s + 2] = fmaf(e[s], fy, acc[4 * s + 2]);
                        acc[4 * s + 3] = fmaf(e[s], fz, acc[4 * s + 3]);
                    }

                    if (!more) break;
                    cur = nxt; t = tn;
                }
            }
        }
    }

    // R1-verified value-split butterfly: lane l ends with full sum of value l.
#pragma unroll
    for (int m = 32; m >= 1; m >>= 1) {
        const bool hi = (lane & m) != 0;
#pragma unroll
        for (int j = 0; j < m; ++j) {
            const float lo_v = acc[j];
            const float hi_v = acc[j + m];
            const float give = hi ? lo_v : hi_v;
            const float keep = hi ? hi_v : lo_v;
            acc[j] = keep + __shfl_xor(give, m, 64);
        }
    }
    const float tot = acc[0];

    if (act && ih == 1) red[pa][lane] = tot;
    __syncthreads();
    if (act && ih == 0) {
        const float sum = tot + red[pa][lane];
        const int s = lane >> 2;
        const int c = lane & 3;
        float scale; int ov;
        if (c == 0) { scale = r_norms[s] * a0[0];     ov = s; }
        else        { scale = r_norms[s] * a1[c - 1]; ov = 16 + 3 * s + (c - 1); }
        out[a * 64 + ov] = sum * scale;
    }
}

extern "C" void kernel_launch(void* const* d_in, const int* in_sizes, int n_in,
                              void* d_out, int out_size, void* d_ws, size_t ws_size,
                              hipStream_t stream) {
    const float* f          = (const float*)d_in[0];
    const float* coords     = (const float*)d_in[1];
    const float* out_coords = (const float*)d_in[2];
    const float* mu         = (const float*)d_in[3];
    const float* r_norms    = (const float*)d_in[4];
    const float* a_norms_0  = (const float*)d_in[5];
    const float* a_norms_1  = (const float*)d_in[6];
    float* out = (float*)d_out;

    const int N = in_sizes[0];       // f is [B=1, N]
    const int A = in_sizes[2] / 3;   // out_coords is [B=1, A, 3]

    sph_one<<<(A + 1) / 2, 256, 0, stream>>>(f, coords, out_coords, mu, r_norms,
                                             a_norms_0, a_norms_1, out, N, A);
}